// Round 5
// baseline (613.422 us; speedup 1.0000x reference)
//
#include <hip/hip_runtime.h>
#include <hip/hip_bf16.h>

typedef __bf16 bf16;
typedef __bf16 bf16x8 __attribute__((ext_vector_type(8)));
typedef __bf16 bf16x4 __attribute__((ext_vector_type(4)));
typedef float f32x4 __attribute__((ext_vector_type(4)));
typedef unsigned int u32;
typedef unsigned short u16;

constexpr int B_ = 4, S = 2048, D = 1024, H = 16, HD = 64;
constexpr int M = B_ * S;  // 8192

#define MFMA(a, b, c) __builtin_amdgcn_mfma_f32_16x16x32_bf16(a, b, c, 0, 0, 0)

// ---- async global->LDS, 16 B per lane (dest = wave-uniform base + lane*16) ----
__device__ inline void gl_lds16(const bf16* g, bf16* l) {
  __builtin_amdgcn_global_load_lds(
      (const __attribute__((address_space(1))) u32*)g,
      (__attribute__((address_space(3))) u32*)l, 16, 0, 0);
}

__device__ inline bf16x8 load8(const void* base, size_t idx, bool isf32) {
  if (isf32) {
    const float* p = (const float*)base + idx;
    const float4 a = *(const float4*)p;
    const float4 b = *(const float4*)(p + 4);
    bf16x8 r;
    r[0] = (bf16)a.x; r[1] = (bf16)a.y; r[2] = (bf16)a.z; r[3] = (bf16)a.w;
    r[4] = (bf16)b.x; r[5] = (bf16)b.y; r[6] = (bf16)b.z; r[7] = (bf16)b.w;
    return r;
  }
  return *(const bf16x8*)((const bf16*)base + idx);
}
__device__ inline float load1(const void* base, size_t idx, bool isf32) {
  return isf32 ? ((const float*)base)[idx] : (float)((const bf16*)base)[idx];
}
// 4 consecutive mask values (idx multiple of 4 -> aligned)
__device__ inline f32x4 load4(const void* base, size_t idx, bool isf32) {
  if (isf32) {
    const float4 v = *(const float4*)((const float*)base + idx);
    return {v.x, v.y, v.z, v.w};
  }
  const bf16x4 v = *(const bf16x4*)((const bf16*)base + idx);
  return {(float)v[0], (float)v[1], (float)v[2], (float)v[3]};
}

// ---------------------------------------------------------------------------
// flag bit0 = inputs are fp32; bit1 = mask has a nonzero element.
// flag is zeroed via hipMemsetAsync before these run.
// ---------------------------------------------------------------------------
__global__ __launch_bounds__(256) void detect_dtype(const uint4* __restrict__ X,
                                                    int* __restrict__ flag) {
  bool hit = false;
  for (int i = blockIdx.x * 256 + threadIdx.x; i < 32768; i += 64 * 256) {
    const uint4 v = X[i];
    const u32 w[4] = {v.x, v.y, v.z, v.w};
#pragma unroll
    for (int j = 0; j < 4; j++) {
      if (((w[j] >> 7) & 0xFFu) == 0xFFu) hit = true;
      if (((w[j] >> 23) & 0xFFu) == 0xFFu) hit = true;
    }
  }
  __shared__ int s;
  if (threadIdx.x == 0) s = 0;
  __syncthreads();
  if (hit) atomicOr(&s, 1);
  __syncthreads();
  if (threadIdx.x == 0 && s) atomicOr(flag, 1);
}

// runs after detect_dtype (stream-ordered): reads bit0 to size the mask scan.
__global__ __launch_bounds__(256) void detect_mask(const uint4* __restrict__ Mk,
                                                   int* __restrict__ flag) {
  const bool isf32 = (*flag & 1) != 0;
  const int n4 = (B_ * S * (isf32 ? 4 : 2)) / 16;  // 2048 (f32) or 1024 (bf16)
  bool nz = false;
  for (int i = blockIdx.x * 256 + threadIdx.x; i < n4; i += 8 * 256) {
    const uint4 v = Mk[i];
    nz |= ((v.x | v.y | v.z | v.w) != 0u);
  }
  __shared__ int s;
  if (threadIdx.x == 0) s = 0;
  __syncthreads();
  if (nz) atomicOr(&s, 1);
  __syncthreads();
  if (threadIdx.x == 0 && s) atomicOr(flag, 2);
}

// ---------------------------------------------------------------------------
// fp32 only: convert X -> Xb (d_out[0,16MB)), W q/k/v -> Wb (d_out+16MB).
// ---------------------------------------------------------------------------
__global__ __launch_bounds__(256) void convert_inputs(
    const void* __restrict__ X, const void* __restrict__ W0,
    const void* __restrict__ W1, const void* __restrict__ W2,
    bf16* __restrict__ Xb, bf16* __restrict__ Wb,
    const int* __restrict__ flagp) {
  if ((*flagp & 1) == 0) return;
  const int seg = blockIdx.y;
  const size_t n = (seg == 0) ? (size_t)M * D : (size_t)D * D;
  const size_t i0 = ((size_t)blockIdx.x * 256 + threadIdx.x) * 8;
  if (i0 >= n) return;
  const void* src = seg == 0 ? X : seg == 1 ? W0 : seg == 2 ? W1 : W2;
  bf16* dst = seg == 0 ? Xb : Wb + (size_t)(seg - 1) * D * D;
  *(bf16x8*)(dst + i0) = load8(src, i0, true);
}

// ---------------------------------------------------------------------------
// QKV GEMM (round-2 m97-structure version, reverted: the 256x256 8-phase port
// regressed ~26us and its counters are invisible below attn's — don't debug
// blind). grid (M/128, D/128, 3), 256 threads, async-staged bf16 A and B.
// z==0: Q*(0.125*log2e) [B,H,S,HD]; z==1: K; z==2: Vt [B,H,HD,S].
// ---------------------------------------------------------------------------
__global__ __launch_bounds__(256) void qkv_gemm(
    const void* __restrict__ X0, const bf16* __restrict__ Xb,
    const void* __restrict__ W0, const void* __restrict__ W1, const void* __restrict__ W2,
    const void* __restrict__ b0, const void* __restrict__ b1, const void* __restrict__ b2,
    bf16* __restrict__ Qo, bf16* __restrict__ Ko, bf16* __restrict__ Vo,
    const bf16* __restrict__ Wb, const int* __restrict__ flagp) {
  const int z = blockIdx.z;
  const bool isf32 = (*flagp & 1) != 0;
  const void* Worig = z == 0 ? W0 : z == 1 ? W1 : W2;
  const void* bias  = z == 0 ? b0 : z == 1 ? b1 : b2;
  bf16* out         = z == 0 ? Qo : z == 1 ? Ko : Vo;
  const bf16* Xs = isf32 ? Xb : (const bf16*)X0;
  const bf16* Ws = isf32 ? (Wb + (size_t)z * D * D) : (const bf16*)Worig;

  __shared__ __align__(16) bf16 As[128 * 32];
  __shared__ __align__(16) bf16 Bs[128 * 32];
  const int tid = threadIdx.x, lane = tid & 63, wave = tid >> 6;
  const int q16 = lane & 15, quad = lane >> 4;
  const int wm = (wave & 1) * 64, wn = (wave >> 1) * 64;
  const int bm = blockIdx.x * 128, bn = blockIdx.y * 128;
  const int r0 = tid >> 2, kg = (tid & 3) * 8;

  f32x4 acc[4][4] = {};

  for (int k0 = 0; k0 < D; k0 += 32) {
    __syncthreads();
    gl_lds16(Xs + (size_t)(bm + r0) * D + k0 + kg,      As + wave * 512 + lane * 8);
    gl_lds16(Xs + (size_t)(bm + 64 + r0) * D + k0 + kg, As + (4 + wave) * 512 + lane * 8);
    gl_lds16(Ws + (size_t)(bn + r0) * D + k0 + kg,      Bs + wave * 512 + lane * 8);
    gl_lds16(Ws + (size_t)(bn + 64 + r0) * D + k0 + kg, Bs + (4 + wave) * 512 + lane * 8);
    __syncthreads();
    bf16x8 af[4], bfr[4];
#pragma unroll
    for (int i = 0; i < 4; i++) {
      af[i]  = *(const bf16x8*)(As + (wm + i * 16 + q16) * 32 + quad * 8);
      bfr[i] = *(const bf16x8*)(Bs + (wn + i * 16 + q16) * 32 + quad * 8);
    }
#pragma unroll
    for (int mi = 0; mi < 4; mi++)
#pragma unroll
      for (int ni = 0; ni < 4; ni++)
        acc[mi][ni] = MFMA(af[mi], bfr[ni], acc[mi][ni]);
  }

  const float scl = (z == 0) ? 0.125f * 1.44269504f : 1.0f;
#pragma unroll
  for (int mi = 0; mi < 4; mi++) {
#pragma unroll
    for (int ni = 0; ni < 4; ni++) {
      const int gn = bn + wn + ni * 16 + q16;
      const float bb = load1(bias, gn, isf32);
      const int h = gn >> 6, hd = gn & 63;
      const int gm0 = bm + wm + mi * 16 + quad * 4;
      const int bidx = gm0 >> 11, s0 = gm0 & 2047;
      if (z == 2) {
        bf16x4 v4;
#pragma unroll
        for (int r = 0; r < 4; r++) v4[r] = (bf16)(acc[mi][ni][r] + bb);
        *(bf16x4*)(out + ((size_t)(bidx * H + h) * HD + hd) * S + s0) = v4;
      } else {
#pragma unroll
        for (int r = 0; r < 4; r++)
          out[((size_t)(bidx * H + h) * S + (s0 + r)) * HD + hd] = (bf16)((acc[mi][ni][r] + bb) * scl);
      }
    }
  }
}

// ---------------------------------------------------------------------------
// Flash attention v8: round-2 body (L2-resident K/V, zero LDS, 4 q-sets/wave)
// + K-ONLY register double-buffer. Rationale: wall is ~10.3k cyc/KV-tile vs
// ~1.3k of issue work -> exposed load latency at 2 waves/SIMD. K-frags are
// consumed immediately at tile top (latency on critical path every tile);
// V/mask are consumed ~500cy after issue (self-hidden). So prefetch only K
// of tile t+1 during tile t (+32 VGPR). Round-1/3 lesson: full double-buffer
// (~270 regs) spills catastrophically; live-set here ~230 <= 256, and
// amdgpu_waves_per_eu(2,2) pins the allocator budget to exactly 256 so it
// doesn't clamp to 128 + spill.
// Q,K: [BH,S,HD]; Vt: [BH,HD,S]; mask: [B,S]; out: [B,S,D]
// ---------------------------------------------------------------------------
__global__ __launch_bounds__(256)
__attribute__((amdgpu_waves_per_eu(2, 2))) void attn(
    const bf16* __restrict__ Q, const bf16* __restrict__ K,
    const bf16* __restrict__ Vt, const void* __restrict__ mask,
    void* __restrict__ outv, const int* __restrict__ flagp) {
  const int fl = *flagp;
  const bool isf32 = (fl & 1) != 0;
  const bool havemask = (fl & 2) != 0;
  const int tid = threadIdx.x, lane = tid & 63, wave = tid >> 6;
  const int q16 = lane & 15, quad = lane >> 4;

  // XCD-grouped decomposition of the 512-block 1-D grid (HW: XCD = bid % 8).
  const int bid = blockIdx.x;
  const int xcd = bid & 7, l = bid >> 3;
  const int bh = (xcd << 3) | (l & 7);   // XCD k handles bh 8k..8k+7
  const int qchunk = l >> 3;             // 0..7
  const int b = bh >> 4, h = bh & 15;
  const int qbase = qchunk * 256 + wave * 64;
  const float L2E = 1.44269504f;

  // Q B-frags: B[k=hd][n=q]: lane holds Q[q16][quad*8+j] per q-set, hd-chunk
  bf16x8 qf[4][2];
#pragma unroll
  for (int qs = 0; qs < 4; qs++) {
    const bf16* qr = Q + ((size_t)bh * S + qbase + qs * 16 + q16) * HD;
    qf[qs][0] = *(const bf16x8*)(qr + quad * 8);
    qf[qs][1] = *(const bf16x8*)(qr + 32 + quad * 8);
  }

  f32x4 o[4][4] = {};   // [qs][hi]  O^T accum: row=hd_local, col=query
  float racc[4] = {};   // per-lane rowsum (this lane's query q16, per q-set)

  const bf16* Kb = K + (size_t)bh * S * HD;
  const bf16* Vb = Vt + (size_t)bh * HD * S;
  const int kprow = 8 * (q16 >> 2) + (q16 & 3);  // lane's permuted-key row part
  const size_t mbase = (size_t)b * S;

#define LOADK(KF_, T_)                                                          \
  {                                                                             \
    const int kt_ = (T_) * 64;                                                  \
    _Pragma("unroll") for (int ki = 0; ki < 4; ki++) {                          \
      const bf16* kr = Kb + (size_t)(kt_ + 32 * (ki >> 1) + 4 * (ki & 1) + kprow) * HD; \
      KF_[ki][0] = *(const bf16x8*)(kr + quad * 8);                             \
      KF_[ki][1] = *(const bf16x8*)(kr + 32 + quad * 8);                        \
    }                                                                           \
  }

// compute tile T_ with KF_; prefetch K of tile T_+1 into KN_ if PF_
#define TILE(KF_, KN_, T_, PF_)                                                 \
  {                                                                             \
    const int kt_ = (T_) * 64;                                                  \
    bf16x8 vf[4][2];                                                            \
    _Pragma("unroll") for (int hi = 0; hi < 4; hi++) {                          \
      const bf16* vr = Vb + (size_t)(hi * 16 + q16) * S + kt_;                  \
      vf[hi][0] = *(const bf16x8*)(vr + quad * 8);                              \
      vf[hi][1] = *(const bf16x8*)(vr + 32 + quad * 8);                         \
    }                                                                           \
    f32x4 mk[4];                                                                \
    if (havemask) {                                                             \
      _Pragma("unroll") for (int ki = 0; ki < 4; ki++) {                        \
        f32x4 mv = load4(mask, mbase + kt_ + 32 * (ki >> 1) + 4 * (ki & 1) + 8 * quad, isf32); \
        _Pragma("unroll") for (int r = 0; r < 4; r++) mk[ki][r] = mv[r] * L2E;  \
      }                                                                         \
    }                                                                           \
    if (PF_) LOADK(KN_, (T_) + 1);                                              \
    _Pragma("unroll") for (int qs = 0; qs < 4; qs++) {                          \
      f32x4 sc[4];                                                              \
      __builtin_amdgcn_s_setprio(1);                                            \
      _Pragma("unroll") for (int ki = 0; ki < 4; ki++) {                        \
        f32x4 zz = {0.f, 0.f, 0.f, 0.f};                                        \
        zz = MFMA(KF_[ki][0], qf[qs][0], zz);                                   \
        sc[ki] = MFMA(KF_[ki][1], qf[qs][1], zz);                               \
      }                                                                         \
      __builtin_amdgcn_s_setprio(0);                                            \
      bf16x8 pb[2];                                                             \
      float rs = 0.f;                                                           \
      _Pragma("unroll") for (int ki = 0; ki < 4; ki++) {                        \
        const int hh = ki >> 1, half = (ki & 1) * 4;                            \
        float p0, p1, p2, p3;                                                   \
        if (havemask) {                                                         \
          p0 = __builtin_amdgcn_exp2f(sc[ki][0] + mk[ki][0]);                   \
          p1 = __builtin_amdgcn_exp2f(sc[ki][1] + mk[ki][1]);                   \
          p2 = __builtin_amdgcn_exp2f(sc[ki][2] + mk[ki][2]);                   \
          p3 = __builtin_amdgcn_exp2f(sc[ki][3] + mk[ki][3]);                   \
        } else {                                                                \
          p0 = __builtin_amdgcn_exp2f(sc[ki][0]);                               \
          p1 = __builtin_amdgcn_exp2f(sc[ki][1]);                               \
          p2 = __builtin_amdgcn_exp2f(sc[ki][2]);                               \
          p3 = __builtin_amdgcn_exp2f(sc[ki][3]);                               \
        }                                                                       \
        rs += ((p0 + p1) + (p2 + p3));                                          \
        pb[hh][half + 0] = (bf16)p0; pb[hh][half + 1] = (bf16)p1;               \
        pb[hh][half + 2] = (bf16)p2; pb[hh][half + 3] = (bf16)p3;               \
      }                                                                         \
      racc[qs] += rs;                                                           \
      __builtin_amdgcn_s_setprio(1);                                            \
      _Pragma("unroll") for (int hi = 0; hi < 4; hi++) {                        \
        o[qs][hi] = MFMA(vf[hi][0], pb[0], o[qs][hi]);                          \
        o[qs][hi] = MFMA(vf[hi][1], pb[1], o[qs][hi]);                          \
      }                                                                         \
      __builtin_amdgcn_s_setprio(0);                                            \
    }                                                                           \
  }

  bf16x8 kA[4][2], kB[4][2];
  LOADK(kA, 0);
#pragma unroll 1
  for (int t = 0; t < 32; t += 2) {
    TILE(kA, kB, t, 1);                  // compute t, prefetch K(t+1)
    TILE(kB, kA, t + 1, (t + 1) < 31);   // compute t+1, prefetch K(t+2)
  }
#undef LOADK
#undef TILE

  // rowsum: reduce across the 4 quads holding the same query q16
#pragma unroll
  for (int qs = 0; qs < 4; qs++) {
    racc[qs] += __shfl_xor(racc[qs], 16);
    racc[qs] += __shfl_xor(racc[qs], 32);
  }

  // epilogue: out[b, qbase+qs*16+q16, h*64 + hi*16 + quad*4 + r] = o/racc
#pragma unroll
  for (int qs = 0; qs < 4; qs++) {
    const float inv = 1.0f / racc[qs];
    const size_t row = (size_t)b * S + qbase + qs * 16 + q16;
#pragma unroll
    for (int hi = 0; hi < 4; hi++) {
      const size_t off = row * D + h * HD + hi * 16 + quad * 4;
      if (isf32) {
        float4 st;
        st.x = o[qs][hi][0] * inv; st.y = o[qs][hi][1] * inv;
        st.z = o[qs][hi][2] * inv; st.w = o[qs][hi][3] * inv;
        *(float4*)((float*)outv + off) = st;
      } else {
        bf16x4 st;
#pragma unroll
        for (int r = 0; r < 4; r++) st[r] = (bf16)(o[qs][hi][r] * inv);
        *(bf16x4*)((bf16*)outv + off) = st;
      }
    }
  }
}

// ---------------------------------------------------------------------------
extern "C" void kernel_launch(void* const* d_in, const int* in_sizes, int n_in,
                              void* d_out, int out_size, void* d_ws, size_t ws_size,
                              hipStream_t stream) {
  const void* X    = d_in[0];
  const void* mask = d_in[1];
  const void* Wq = d_in[2]; const void* bq = d_in[3];
  const void* Wk = d_in[4]; const void* bk = d_in[5];
  const void* Wv = d_in[6]; const void* bv = d_in[7];

  const size_t elems = (size_t)M * D;  // 8 Mi
  bf16* Qw = (bf16*)d_ws;
  bf16* Kw = Qw + elems;
  bf16* Vw = Kw + elems;
  int* flag = (int*)(Vw + elems);

  // fp32 case: d_out (32 MB) stages bf16 X (16MB) + W (6MB).
  bf16* Xb = (bf16*)d_out;
  bf16* Wb = Xb + elems;

  hipMemsetAsync(flag, 0, sizeof(int), stream);
  detect_dtype<<<64, 256, 0, stream>>>((const uint4*)X, flag);
  detect_mask<<<8, 256, 0, stream>>>((const uint4*)mask, flag);
  convert_inputs<<<dim3(4096, 4), 256, 0, stream>>>(X, Wq, Wk, Wv, Xb, Wb, flag);
  qkv_gemm<<<dim3(M / 128, D / 128, 3), 256, 0, stream>>>(
      X, Xb, Wq, Wk, Wv, bq, bk, bv, Qw, Kw, Vw, Wb, flag);
  attn<<<dim3(512), 256, 0, stream>>>(Qw, Kw, Vw, mask, d_out, flag);
}

// Round 6
// 240.277 us; speedup vs baseline: 2.5530x; 2.5530x over previous
//
#include <hip/hip_runtime.h>
#include <hip/hip_bf16.h>

typedef __bf16 bf16;
typedef __bf16 bf16x8 __attribute__((ext_vector_type(8)));
typedef __bf16 bf16x4 __attribute__((ext_vector_type(4)));
typedef float f32x4 __attribute__((ext_vector_type(4)));
typedef unsigned int u32;
typedef unsigned short u16;

constexpr int B_ = 4, S = 2048, D = 1024, H = 16, HD = 64;
constexpr int M = B_ * S;  // 8192

#define MFMA(a, b, c) __builtin_amdgcn_mfma_f32_16x16x32_bf16(a, b, c, 0, 0, 0)

// ---- async global->LDS, 16 B per lane (dest = wave-uniform base + lane*16) ----
__device__ inline void gl_lds16(const bf16* g, bf16* l) {
  __builtin_amdgcn_global_load_lds(
      (const __attribute__((address_space(1))) u32*)g,
      (__attribute__((address_space(3))) u32*)l, 16, 0, 0);
}

__device__ inline bf16x8 load8(const void* base, size_t idx, bool isf32) {
  if (isf32) {
    const float* p = (const float*)base + idx;
    const float4 a = *(const float4*)p;
    const float4 b = *(const float4*)(p + 4);
    bf16x8 r;
    r[0] = (bf16)a.x; r[1] = (bf16)a.y; r[2] = (bf16)a.z; r[3] = (bf16)a.w;
    r[4] = (bf16)b.x; r[5] = (bf16)b.y; r[6] = (bf16)b.z; r[7] = (bf16)b.w;
    return r;
  }
  return *(const bf16x8*)((const bf16*)base + idx);
}
__device__ inline float load1(const void* base, size_t idx, bool isf32) {
  return isf32 ? ((const float*)base)[idx] : (float)((const bf16*)base)[idx];
}
// 4 consecutive mask values (idx multiple of 4 -> aligned)
__device__ inline f32x4 load4(const void* base, size_t idx, bool isf32) {
  if (isf32) {
    const float4 v = *(const float4*)((const float*)base + idx);
    return {v.x, v.y, v.z, v.w};
  }
  const bf16x4 v = *(const bf16x4*)((const bf16*)base + idx);
  return {(float)v[0], (float)v[1], (float)v[2], (float)v[3]};
}

// attn LDS bank swizzle: 3 XOR bits (byte bits 4-6) chosen so the fragment-read
// row set {8a+b : a<4,b<4} (rows mod 8 = lane mod 8 pattern) spreads uniformly
// over all 8 16B-slots of a 128B row. swz(row) uses row bits {0,1,3}.
__device__ inline int kvswz(int row) {
  return (((row & 3) | (((row >> 3) & 1) << 2)) << 4);
}
__device__ inline bf16x8 ldsf(const bf16* reg, int row, int cb) {
  return *(const bf16x8*)((const char*)reg + row * 128 + (cb ^ kvswz(row)));
}

// ---------------------------------------------------------------------------
// flag bit0 = inputs are fp32; bit1 = mask has a nonzero element.
// flag is zeroed via hipMemsetAsync before these run.
// ---------------------------------------------------------------------------
__global__ __launch_bounds__(256) void detect_dtype(const uint4* __restrict__ X,
                                                    int* __restrict__ flag) {
  bool hit = false;
  for (int i = blockIdx.x * 256 + threadIdx.x; i < 32768; i += 64 * 256) {
    const uint4 v = X[i];
    const u32 w[4] = {v.x, v.y, v.z, v.w};
#pragma unroll
    for (int j = 0; j < 4; j++) {
      if (((w[j] >> 7) & 0xFFu) == 0xFFu) hit = true;
      if (((w[j] >> 23) & 0xFFu) == 0xFFu) hit = true;
    }
  }
  __shared__ int s;
  if (threadIdx.x == 0) s = 0;
  __syncthreads();
  if (hit) atomicOr(&s, 1);
  __syncthreads();
  if (threadIdx.x == 0 && s) atomicOr(flag, 1);
}

// runs after detect_dtype (stream-ordered): reads bit0 to size the mask scan.
__global__ __launch_bounds__(256) void detect_mask(const uint4* __restrict__ Mk,
                                                   int* __restrict__ flag) {
  const bool isf32 = (*flag & 1) != 0;
  const int n4 = (B_ * S * (isf32 ? 4 : 2)) / 16;  // 2048 (f32) or 1024 (bf16)
  bool nz = false;
  for (int i = blockIdx.x * 256 + threadIdx.x; i < n4; i += 8 * 256) {
    const uint4 v = Mk[i];
    nz |= ((v.x | v.y | v.z | v.w) != 0u);
  }
  __shared__ int s;
  if (threadIdx.x == 0) s = 0;
  __syncthreads();
  if (nz) atomicOr(&s, 1);
  __syncthreads();
  if (threadIdx.x == 0 && s) atomicOr(flag, 2);
}

// ---------------------------------------------------------------------------
// fp32 only: convert X -> Xb (d_out[0,16MB)), W q/k/v -> Wb (d_out+16MB).
// ---------------------------------------------------------------------------
__global__ __launch_bounds__(256) void convert_inputs(
    const void* __restrict__ X, const void* __restrict__ W0,
    const void* __restrict__ W1, const void* __restrict__ W2,
    bf16* __restrict__ Xb, bf16* __restrict__ Wb,
    const int* __restrict__ flagp) {
  if ((*flagp & 1) == 0) return;
  const int seg = blockIdx.y;
  const size_t n = (seg == 0) ? (size_t)M * D : (size_t)D * D;
  const size_t i0 = ((size_t)blockIdx.x * 256 + threadIdx.x) * 8;
  if (i0 >= n) return;
  const void* src = seg == 0 ? X : seg == 1 ? W0 : seg == 2 ? W1 : W2;
  bf16* dst = seg == 0 ? Xb : Wb + (size_t)(seg - 1) * D * D;
  *(bf16x8*)(dst + i0) = load8(src, i0, true);
}

// ---------------------------------------------------------------------------
// QKV GEMM (round-2 m97-structure, known-good ~130us). grid (M/128, D/128, 3).
// z==0: Q*(0.125*log2e) [B,H,S,HD]; z==1: K; z==2: Vt [B,H,HD,S].
// ---------------------------------------------------------------------------
__global__ __launch_bounds__(256) void qkv_gemm(
    const void* __restrict__ X0, const bf16* __restrict__ Xb,
    const void* __restrict__ W0, const void* __restrict__ W1, const void* __restrict__ W2,
    const void* __restrict__ b0, const void* __restrict__ b1, const void* __restrict__ b2,
    bf16* __restrict__ Qo, bf16* __restrict__ Ko, bf16* __restrict__ Vo,
    const bf16* __restrict__ Wb, const int* __restrict__ flagp) {
  const int z = blockIdx.z;
  const bool isf32 = (*flagp & 1) != 0;
  const void* Worig = z == 0 ? W0 : z == 1 ? W1 : W2;
  const void* bias  = z == 0 ? b0 : z == 1 ? b1 : b2;
  bf16* out         = z == 0 ? Qo : z == 1 ? Ko : Vo;
  const bf16* Xs = isf32 ? Xb : (const bf16*)X0;
  const bf16* Ws = isf32 ? (Wb + (size_t)z * D * D) : (const bf16*)Worig;

  __shared__ __align__(16) bf16 As[128 * 32];
  __shared__ __align__(16) bf16 Bs[128 * 32];
  const int tid = threadIdx.x, lane = tid & 63, wave = tid >> 6;
  const int q16 = lane & 15, quad = lane >> 4;
  const int wm = (wave & 1) * 64, wn = (wave >> 1) * 64;
  const int bm = blockIdx.x * 128, bn = blockIdx.y * 128;
  const int r0 = tid >> 2, kg = (tid & 3) * 8;

  f32x4 acc[4][4] = {};

  for (int k0 = 0; k0 < D; k0 += 32) {
    __syncthreads();
    gl_lds16(Xs + (size_t)(bm + r0) * D + k0 + kg,      As + wave * 512 + lane * 8);
    gl_lds16(Xs + (size_t)(bm + 64 + r0) * D + k0 + kg, As + (4 + wave) * 512 + lane * 8);
    gl_lds16(Ws + (size_t)(bn + r0) * D + k0 + kg,      Bs + wave * 512 + lane * 8);
    gl_lds16(Ws + (size_t)(bn + 64 + r0) * D + k0 + kg, Bs + (4 + wave) * 512 + lane * 8);
    __syncthreads();
    bf16x8 af[4], bfr[4];
#pragma unroll
    for (int i = 0; i < 4; i++) {
      af[i]  = *(const bf16x8*)(As + (wm + i * 16 + q16) * 32 + quad * 8);
      bfr[i] = *(const bf16x8*)(Bs + (wn + i * 16 + q16) * 32 + quad * 8);
    }
#pragma unroll
    for (int mi = 0; mi < 4; mi++)
#pragma unroll
      for (int ni = 0; ni < 4; ni++)
        acc[mi][ni] = MFMA(af[mi], bfr[ni], acc[mi][ni]);
  }

  const float scl = (z == 0) ? 0.125f * 1.44269504f : 1.0f;
#pragma unroll
  for (int mi = 0; mi < 4; mi++) {
#pragma unroll
    for (int ni = 0; ni < 4; ni++) {
      const int gn = bn + wn + ni * 16 + q16;
      const float bb = load1(bias, gn, isf32);
      const int h = gn >> 6, hd = gn & 63;
      const int gm0 = bm + wm + mi * 16 + quad * 4;
      const int bidx = gm0 >> 11, s0 = gm0 & 2047;
      if (z == 2) {
        bf16x4 v4;
#pragma unroll
        for (int r = 0; r < 4; r++) v4[r] = (bf16)(acc[mi][ni][r] + bb);
        *(bf16x4*)(out + ((size_t)(bidx * H + h) * HD + hd) * S + s0) = v4;
      } else {
#pragma unroll
        for (int r = 0; r < 4; r++)
          out[((size_t)(bidx * H + h) * S + (s0 + r)) * HD + hd] = (bf16)((acc[mi][ni][r] + bb) * scl);
      }
    }
  }
}

// ---------------------------------------------------------------------------
// Flash attention v9: LDS-shared K/V. Register ledger (r1/r3/r5 lesson:
// per-wave TOTAL budget = 512/waves_per_EU, acc comes off the top):
//   target 4 waves/SIMD -> 128/wave = acc 32 (o[2][4]) + arch cap 96.
//   arch peak ~90: qf 16 + kf 32 (QK phase only) + sc 16 + pb 16 + vf 8 transient.
// The 4 waves of a block previously each loaded the SAME K/V tile into
// private regs (64 VGPR/wave, quadruple traffic). Now: tile staged once to
// LDS (2 x 16KB double buffer) via gl_lds16 at iteration top (T14 issue-early),
// consumed after the compute phase; one __syncthreads (vmcnt drain) per tile.
// Swizzle both-sides (rule 21): linear gl_lds dest + inverse-XOR global source
// column + XOR on ds_read. 2 q-sets/wave, grid 1024 XCD-grouped = 4 blocks/CU
// exactly (no tail). MFMA dataflow (key permutation, score->pb pack, epilogue)
// identical to the r2/r3-verified math.
// Q,K: [BH,S,HD]; Vt: [BH,HD,S]; mask: [B,S]; out: [B,S,D]
// ---------------------------------------------------------------------------
__global__ __launch_bounds__(256, 4) void attn(
    const bf16* __restrict__ Q, const bf16* __restrict__ K,
    const bf16* __restrict__ Vt, const void* __restrict__ mask,
    void* __restrict__ outv, const int* __restrict__ flagp) {
  const int fl = *flagp;
  const bool isf32 = (fl & 1) != 0;
  const bool havemask = (fl & 2) != 0;
  const int tid = threadIdx.x, lane = tid & 63, wave = tid >> 6;
  const int q16 = lane & 15, quad = lane >> 4;

  // XCD-grouped decomposition of the 1024-block grid (HW: XCD = bid % 8).
  const int bid = blockIdx.x;
  const int xcd = bid & 7, l = bid >> 3;       // l: 0..127
  const int bh = (xcd << 3) | (l & 7);         // XCD k handles bh 8k..8k+7
  const int qchunk = l >> 3;                   // 0..15
  const int b = bh >> 4, h = bh & 15;
  const int qbase = qchunk * 128 + wave * 32;  // wave covers 32 queries
  const float L2E = 1.44269504f;

  __shared__ __align__(16) bf16 kv[2][8192];   // [buf][K 4096 elems | V 4096]

  // Q B-frags
  bf16x8 qf[2][2];
#pragma unroll
  for (int qs = 0; qs < 2; qs++) {
    const bf16* qr = Q + ((size_t)bh * S + qbase + qs * 16 + q16) * HD;
    qf[qs][0] = *(const bf16x8*)(qr + quad * 8);
    qf[qs][1] = *(const bf16x8*)(qr + 32 + quad * 8);
  }

  f32x4 o[2][4] = {};   // [qs][hi]  O^T accum
  float racc[2] = {};

  const bf16* Kb = K + (size_t)bh * S * HD;
  const bf16* Vb = Vt + (size_t)bh * HD * S;
  const int kprow = 8 * (q16 >> 2) + (q16 & 3);
  const size_t mbase = (size_t)b * S;

  // staging: per wave, 4 x gl_lds16 (K halves i=0,1 then V halves).
  // LDS linear dest byte (region*4096 + wave*1024 + lane*16) holds logical
  // (row = region_row, col = pc ^ kvswz(row)) so ldsf's XOR read is correct.
  const int srow8 = wave * 8 + (lane >> 3);    // 0..31 within half
  const int pc = (lane & 7) * 16;              // physical col byte
#define STAGE(BUFP_, T_)                                                       \
  {                                                                            \
    const int kt_ = (T_) * 64;                                                 \
    _Pragma("unroll") for (int i = 0; i < 2; i++) {                            \
      const int key = i * 32 + srow8;                                          \
      gl_lds16(Kb + (size_t)(kt_ + key) * HD + ((pc ^ kvswz(key)) >> 1),       \
               (BUFP_) + i * 2048 + wave * 512 + lane * 8);                    \
    }                                                                          \
    _Pragma("unroll") for (int i = 0; i < 2; i++) {                            \
      const int vrow = i * 32 + srow8;                                         \
      gl_lds16(Vb + (size_t)vrow * S + kt_ + ((pc ^ kvswz(vrow)) >> 1),        \
               (BUFP_) + 4096 + i * 2048 + wave * 512 + lane * 8);             \
    }                                                                          \
  }

  STAGE(&kv[0][0], 0);
  __syncthreads();   // drains vmcnt(0): tile 0 staged

#pragma unroll 1
  for (int t = 0; t < 32; ++t) {
    if (t + 1 < 32) STAGE(&kv[(t + 1) & 1][0], t + 1);  // issue early (T14)
    const bf16* Kl = &kv[t & 1][0];
    const bf16* Vl = Kl + 4096;
    const int kt = t * 64;

    // K A-frags from LDS (permuted key rows)
    bf16x8 kf[4][2];
#pragma unroll
    for (int ki = 0; ki < 4; ki++) {
      const int krow = 32 * (ki >> 1) + 4 * (ki & 1) + kprow;
      kf[ki][0] = ldsf(Kl, krow, quad * 16);
      kf[ki][1] = ldsf(Kl, krow, 64 + quad * 16);
    }

    bf16x8 pb[2][2];
#pragma unroll
    for (int qs = 0; qs < 2; qs++) {
      f32x4 sc[4];
      __builtin_amdgcn_s_setprio(1);
#pragma unroll
      for (int ki = 0; ki < 4; ki++) {
        f32x4 zz = {0.f, 0.f, 0.f, 0.f};
        zz = MFMA(kf[ki][0], qf[qs][0], zz);
        sc[ki] = MFMA(kf[ki][1], qf[qs][1], zz);
      }
      __builtin_amdgcn_s_setprio(0);
      float rs = 0.f;
#pragma unroll
      for (int ki = 0; ki < 4; ki++) {
        const int hh = ki >> 1, half = (ki & 1) * 4;
        float p0, p1, p2, p3;
        if (havemask) {
          f32x4 mv = load4(mask, mbase + kt + 32 * (ki >> 1) + 4 * (ki & 1) + 8 * quad, isf32);
          p0 = __builtin_amdgcn_exp2f(sc[ki][0] + mv[0] * L2E);
          p1 = __builtin_amdgcn_exp2f(sc[ki][1] + mv[1] * L2E);
          p2 = __builtin_amdgcn_exp2f(sc[ki][2] + mv[2] * L2E);
          p3 = __builtin_amdgcn_exp2f(sc[ki][3] + mv[3] * L2E);
        } else {
          p0 = __builtin_amdgcn_exp2f(sc[ki][0]);
          p1 = __builtin_amdgcn_exp2f(sc[ki][1]);
          p2 = __builtin_amdgcn_exp2f(sc[ki][2]);
          p3 = __builtin_amdgcn_exp2f(sc[ki][3]);
        }
        rs += ((p0 + p1) + (p2 + p3));
        pb[qs][hh][half + 0] = (bf16)p0; pb[qs][hh][half + 1] = (bf16)p1;
        pb[qs][hh][half + 2] = (bf16)p2; pb[qs][hh][half + 3] = (bf16)p3;
      }
      racc[qs] += rs;
    }

    // O^T += Vt . P^T ; V frags transient (8 VGPR), shared by both q-sets
    __builtin_amdgcn_s_setprio(1);
#pragma unroll
    for (int hi = 0; hi < 4; hi++) {
      const int vrow = hi * 16 + q16;
      const bf16x8 v0 = ldsf(Vl, vrow, quad * 16);
      const bf16x8 v1 = ldsf(Vl, vrow, 64 + quad * 16);
      o[0][hi] = MFMA(v0, pb[0][0], o[0][hi]);
      o[0][hi] = MFMA(v1, pb[0][1], o[0][hi]);
      o[1][hi] = MFMA(v0, pb[1][0], o[1][hi]);
      o[1][hi] = MFMA(v1, pb[1][1], o[1][hi]);
    }
    __builtin_amdgcn_s_setprio(0);

    __syncthreads();  // drains stage(t+1) vmcnt + orders buffer reuse
  }
#undef STAGE

  // rowsum: reduce across the 4 quads holding the same query q16
#pragma unroll
  for (int qs = 0; qs < 2; qs++) {
    racc[qs] += __shfl_xor(racc[qs], 16);
    racc[qs] += __shfl_xor(racc[qs], 32);
  }

  // epilogue: out[b, qbase+qs*16+q16, h*64 + hi*16 + quad*4 + r] = o/racc
#pragma unroll
  for (int qs = 0; qs < 2; qs++) {
    const float inv = 1.0f / racc[qs];
    const size_t row = (size_t)b * S + qbase + qs * 16 + q16;
#pragma unroll
    for (int hi = 0; hi < 4; hi++) {
      const size_t off = row * D + h * HD + hi * 16 + quad * 4;
      if (isf32) {
        float4 st;
        st.x = o[qs][hi][0] * inv; st.y = o[qs][hi][1] * inv;
        st.z = o[qs][hi][2] * inv; st.w = o[qs][hi][3] * inv;
        *(float4*)((float*)outv + off) = st;
      } else {
        bf16x4 st;
#pragma unroll
        for (int r = 0; r < 4; r++) st[r] = (bf16)(o[qs][hi][r] * inv);
        *(bf16x4*)((bf16*)outv + off) = st;
      }
    }
  }
}

// ---------------------------------------------------------------------------
extern "C" void kernel_launch(void* const* d_in, const int* in_sizes, int n_in,
                              void* d_out, int out_size, void* d_ws, size_t ws_size,
                              hipStream_t stream) {
  const void* X    = d_in[0];
  const void* mask = d_in[1];
  const void* Wq = d_in[2]; const void* bq = d_in[3];
  const void* Wk = d_in[4]; const void* bk = d_in[5];
  const void* Wv = d_in[6]; const void* bv = d_in[7];

  const size_t elems = (size_t)M * D;  // 8 Mi
  bf16* Qw = (bf16*)d_ws;
  bf16* Kw = Qw + elems;
  bf16* Vw = Kw + elems;
  int* flag = (int*)(Vw + elems);

  // fp32 case: d_out (32 MB) stages bf16 X (16MB) + W (6MB).
  bf16* Xb = (bf16*)d_out;
  bf16* Wb = Xb + elems;

  hipMemsetAsync(flag, 0, sizeof(int), stream);
  detect_dtype<<<64, 256, 0, stream>>>((const uint4*)X, flag);
  detect_mask<<<8, 256, 0, stream>>>((const uint4*)mask, flag);
  convert_inputs<<<dim3(4096, 4), 256, 0, stream>>>(X, Wq, Wk, Wv, Xb, Wb, flag);
  qkv_gemm<<<dim3(M / 128, D / 128, 3), 256, 0, stream>>>(
      X, Xb, Wq, Wk, Wv, bq, bk, bv, Qw, Kw, Vw, Wb, flag);
  attn<<<dim3(1024), 256, 0, stream>>>(Qw, Kw, Vw, mask, d_out, flag);
}